// Round 21
// baseline (242.859 us; speedup 1.0000x reference)
//
#include <hip/hip_runtime.h>
#include <math.h>

#define DIMC 256
#define NH 8
#define NPIX 16384          // 128*128
#define BATCH 16
#define ATT_SCALE 0.17677669529663687f   // 1/sqrt(32)
#define LN_EPS 1e-5f
#define NBLK_S 8            // n-splits in k_s (2048 n each)

typedef float vfloat4 __attribute__((ext_vector_type(4)));   // native vector for nt store

// ---------------------------------------------------------------------------
// K0: qkT[b][c][h], 512 blocks = 16 b x 32 c-slabs.
// ---------------------------------------------------------------------------
__global__ __launch_bounds__(256) void k_qk(const float* __restrict__ audio,
                                            const float* __restrict__ Wq,
                                            const float* __restrict__ Wkv,
                                            float* __restrict__ qkT) {
    const int blk = blockIdx.x;
    const int b   = blk >> 5;
    const int c0  = (blk & 31) * 8;
    const int t   = threadIdx.x;
    __shared__ float aud[DIMC];
    __shared__ float qL[DIMC];
    aud[t] = audio[b * DIMC + t];
    __syncthreads();
    {
        const float* wr = Wq + (size_t)t * DIMC;
        float acc = 0.f;
        for (int c = 0; c < DIMC; c += 4) {
            float4 w = *(const float4*)(wr + c);
            acc = fmaf(w.x, aud[c],     acc);
            acc = fmaf(w.y, aud[c + 1], acc);
            acc = fmaf(w.z, aud[c + 2], acc);
            acc = fmaf(w.w, aud[c + 3], acc);
        }
        qL[t] = acc;
    }
    __syncthreads();
    if (t < 64) {
        const int c = c0 + (t & 7);
        const int h = t >> 3;
        float acc = 0.f;
#pragma unroll
        for (int d = 0; d < 32; ++d)
            acc = fmaf(qL[h * 32 + d], Wkv[(size_t)(h * 32 + d) * DIMC + c], acc);
        qkT[((size_t)b * DIMC + c) * NH + h] = ATT_SCALE * acc;
    }
}

// ---------------------------------------------------------------------------
// K1: attn pass (R9 verbatim). 512 blocks x 256 thr, float2, unroll 8.
// ---------------------------------------------------------------------------
__global__ __launch_bounds__(256) void k_attn(const float* __restrict__ fm,
                                              const float* __restrict__ qkT,
                                              float* __restrict__ a) {
    int blk  = blockIdx.x;          // 512 = b*32 + nblk
    int b    = blk >> 5;
    int nblk = blk & 31;
    int t    = threadIdx.x;

    const int n0 = nblk * 512 + t * 2;
    const float* fmb = fm + (size_t)b * DIMC * NPIX + n0;
    const float* qb  = qkT + (size_t)b * DIMC * NH;

    float a0[NH], a1[NH];
#pragma unroll
    for (int h = 0; h < NH; ++h) { a0[h] = 0.f; a1[h] = 0.f; }

#pragma unroll 8
    for (int c = 0; c < DIMC; ++c) {
        float2 v  = *(const float2*)(fmb + (size_t)c * NPIX);
        float4 q0 = *(const float4*)(qb + c * NH);       // uniform -> s_load
        float4 q1 = *(const float4*)(qb + c * NH + 4);
        a0[0] = fmaf(v.x, q0.x, a0[0]); a1[0] = fmaf(v.y, q0.x, a1[0]);
        a0[1] = fmaf(v.x, q0.y, a0[1]); a1[1] = fmaf(v.y, q0.y, a1[1]);
        a0[2] = fmaf(v.x, q0.z, a0[2]); a1[2] = fmaf(v.y, q0.z, a1[2]);
        a0[3] = fmaf(v.x, q0.w, a0[3]); a1[3] = fmaf(v.y, q0.w, a1[3]);
        a0[4] = fmaf(v.x, q1.x, a0[4]); a1[4] = fmaf(v.y, q1.x, a1[4]);
        a0[5] = fmaf(v.x, q1.y, a0[5]); a1[5] = fmaf(v.y, q1.y, a1[5]);
        a0[6] = fmaf(v.x, q1.z, a0[6]); a1[6] = fmaf(v.y, q1.z, a1[6]);
        a0[7] = fmaf(v.x, q1.w, a0[7]); a1[7] = fmaf(v.y, q1.w, a1[7]);
    }

#pragma unroll
    for (int h = 0; h < NH; ++h) {
        float2 o;
        o.x = rintf(fminf(fmaxf(a0[h], 0.f), 4.f)) * 0.25f;
        o.y = rintf(fminf(fmaxf(a1[h], 0.f), 4.f)) * 0.25f;
        *(float2*)(a + ((size_t)b * NH + h) * NPIX + n0) = o;
    }
}

// ---------------------------------------------------------------------------
// K2: s partials. 2048 blocks (XCD-swizzled) = 16 b x 8 nblk x 16 cblk;
// 8 blk/CU = 32 waves/CU (TLP x2 vs R20). Thread = (c_l 16, nq 16): owns one
// c, n-quads strided by 64 within a 2048-n slab (j < 32). Identical 4x256-B
// segment pattern per wave instruction as the proven R9/R20 kernel.
// ---------------------------------------------------------------------------
__global__ __launch_bounds__(256) void k_s(const float* __restrict__ fm,
                                           const float* __restrict__ a,
                                           float* __restrict__ s_part) {
    int d    = blockIdx.x;
    int blk  = (d & 7) * 256 + (d >> 3);   // bijective: 2048 = 8 x 256
    int b    = blk >> 7;                   // 128 blocks per b
    int nblk = (blk >> 4) & 7;
    int cblk = blk & 15;
    int t    = threadIdx.x;
    int c_l  = t >> 4;
    int nq   = t & 15;
    int c    = cblk * 16 + c_l;
    const int n0 = nblk * 2048;

    const float* fr = fm + ((size_t)b * DIMC + c) * NPIX + n0 + nq * 4;
    const float* ab = a + (size_t)b * NH * NPIX + n0 + nq * 4;

    float acc[NH];
#pragma unroll
    for (int h = 0; h < NH; ++h) acc[h] = 0.f;

#pragma unroll 4
    for (int j = 0; j < 32; ++j) {
        float4 v = *(const float4*)(fr + j * 64);
#pragma unroll
        for (int h = 0; h < NH; ++h) {
            float4 av = *(const float4*)(ab + (size_t)h * NPIX + j * 64);
            acc[h] += fmaf(v.x, av.x, fmaf(v.y, av.y, fmaf(v.z, av.z, v.w * av.w)));
        }
    }

    __shared__ float red[256 * NH];    // 8 KB
#pragma unroll
    for (int h = 0; h < NH; ++h) red[t * NH + h] = acc[h];
    __syncthreads();

    if (t < 128) {
        int cl = t >> 3, h = t & 7;
        float sum = 0.f;
#pragma unroll
        for (int q = 0; q < 16; ++q)
            sum += red[(cl * 16 + q) * NH + h];
        s_part[(((size_t)b * NBLK_S + nblk) * NH + h) * DIMC + cblk * 16 + cl] = sum;
    }
}

// ---------------------------------------------------------------------------
// K3: s = sum_slab s_part ; x = Wv*s ; p = Wp*x + bp ; LN ; spike -> scale
// ---------------------------------------------------------------------------
__global__ __launch_bounds__(256) void k_scale(const float* __restrict__ s_part,
                                               const float* __restrict__ Wkv,
                                               const float* __restrict__ Wp,
                                               const float* __restrict__ bp,
                                               const float* __restrict__ g,
                                               const float* __restrict__ beta,
                                               float* __restrict__ scale) {
    int b = blockIdx.x;
    int t = threadIdx.x;
    __shared__ float sL[NH][DIMC];
    __shared__ float xL[DIMC];
    __shared__ float red[8];
    __shared__ float mu_s, var_s;

    for (int h = 0; h < NH; ++h) {
        float acc = 0.f;
        for (int sl = 0; sl < NBLK_S; ++sl)
            acc += s_part[(((size_t)b * NBLK_S + sl) * NH + h) * DIMC + t];
        sL[h][t] = acc;
    }
    __syncthreads();

    {
        const float* wr = Wkv + (size_t)(DIMC + t) * DIMC;
        const float* sr = sL[t >> 5];
        float acc = 0.f;
        for (int cc = 0; cc < DIMC; cc += 4) {
            float4 w = *(const float4*)(wr + cc);
            acc = fmaf(w.x, sr[cc],     acc);
            acc = fmaf(w.y, sr[cc + 1], acc);
            acc = fmaf(w.z, sr[cc + 2], acc);
            acc = fmaf(w.w, sr[cc + 3], acc);
        }
        xL[t] = acc;
    }
    __syncthreads();

    float p;
    {
        const float* wr = Wp + (size_t)t * DIMC;
        float acc = 0.f;
        for (int i = 0; i < DIMC; i += 4) {
            float4 w = *(const float4*)(wr + i);
            acc = fmaf(w.x, xL[i],     acc);
            acc = fmaf(w.y, xL[i + 1], acc);
            acc = fmaf(w.z, xL[i + 2], acc);
            acc = fmaf(w.w, xL[i + 3], acc);
        }
        p = acc + bp[t];
    }

    int lane = t & 63, wid = t >> 6;
    float r = p;
#pragma unroll
    for (int off = 32; off > 0; off >>= 1) r += __shfl_down(r, off);
    if (lane == 0) red[wid] = r;
    __syncthreads();
    if (t == 0) mu_s = (red[0] + red[1] + red[2] + red[3]) * (1.f / 256.f);
    __syncthreads();
    float mu = mu_s;
    float dd = p - mu;
    float r2 = dd * dd;
#pragma unroll
    for (int off = 32; off > 0; off >>= 1) r2 += __shfl_down(r2, off);
    if (lane == 0) red[4 + wid] = r2;
    __syncthreads();
    if (t == 0) var_s = (red[4] + red[5] + red[6] + red[7]) * (1.f / 256.f);
    __syncthreads();

    float ln = dd * (1.0f / sqrtf(var_s + LN_EPS)) * g[t] + beta[t];
    scale[b * DIMC + t] = rintf(fminf(fmaxf(ln, 0.f), 4.f)) * 0.25f;
}

// ---------------------------------------------------------------------------
// K4: out = fm * scale[b][c], NT stores, coalesced dual-issue (R20-verified).
// ---------------------------------------------------------------------------
__global__ __launch_bounds__(256) void k_out(const float* __restrict__ fm,
                                             const float* __restrict__ scale,
                                             float* __restrict__ out) {
    const size_t total4 = (size_t)BATCH * DIMC * NPIX / 4;   // 16,777,216
    const size_t tile   = 512;                                // float4 per block-iter
    const size_t stride = (size_t)gridDim.x * tile;
    const int t = threadIdx.x;
    for (size_t base = (size_t)blockIdx.x * tile; base < total4; base += stride) {
        size_t i0 = base + t;
        size_t i1 = base + t + 256;
        vfloat4 v0 = *(const vfloat4*)(fm + i0 * 4);
        vfloat4 v1 = *(const vfloat4*)(fm + i1 * 4);
        float s0 = scale[i0 >> 12];
        float s1 = scale[i1 >> 12];
        vfloat4 o0 = v0 * s0;
        vfloat4 o1 = v1 * s1;
        __builtin_nontemporal_store(o0, (vfloat4*)(out + i0 * 4));
        __builtin_nontemporal_store(o1, (vfloat4*)(out + i1 * 4));
    }
}

// ---------------------------------------------------------------------------
extern "C" void kernel_launch(void* const* d_in, const int* in_sizes, int n_in,
                              void* d_out, int out_size, void* d_ws, size_t ws_size,
                              hipStream_t stream) {
    (void)in_sizes; (void)n_in; (void)out_size; (void)ws_size;
    const float* fm    = (const float*)d_in[0];
    const float* audio = (const float*)d_in[1];
    const float* Wq    = (const float*)d_in[2];
    const float* Wkv   = (const float*)d_in[3];
    const float* Wp    = (const float*)d_in[4];
    const float* bp    = (const float*)d_in[5];
    const float* g     = (const float*)d_in[6];
    const float* beta  = (const float*)d_in[7];
    float* out = (float*)d_out;

    char* ws = (char*)d_ws;
    float* qkT    = (float*)(ws);                                   // 128 KB
    float* a      = (float*)(ws + (size_t)131072);                  // 8 MB
    float* s_part = (float*)(ws + (size_t)131072 + 8388608);        // 1 MB
    float* scale  = (float*)(ws + (size_t)131072 + 8388608 + 1048576); // 16 KB

    hipLaunchKernelGGL(k_qk,    dim3(512),        dim3(256), 0, stream, audio, Wq, Wkv, qkT);
    hipLaunchKernelGGL(k_attn,  dim3(512),        dim3(256), 0, stream, fm, qkT, a);
    hipLaunchKernelGGL(k_s,     dim3(2048),       dim3(256), 0, stream, fm, a, s_part);
    hipLaunchKernelGGL(k_scale, dim3(BATCH),      dim3(256), 0, stream, s_part, Wkv, Wp, bp, g, beta, scale);
    hipLaunchKernelGGL(k_out,   dim3(2048),       dim3(256), 0, stream, fm, scale, out);
}

// Round 22
// 213.605 us; speedup vs baseline: 1.1370x; 1.1370x over previous
//
#include <hip/hip_runtime.h>
#include <math.h>

#define DIMC 256
#define NH 8
#define NPIX 16384          // 128*128
#define BATCH 16
#define ATT_SCALE 0.17677669529663687f   // 1/sqrt(32)
#define LN_EPS 1e-5f
#define NBLK_S 16           // n-slabs in k_s (1024 n each)

typedef float vfloat4 __attribute__((ext_vector_type(4)));   // native vector for nt store

// ---------------------------------------------------------------------------
// K0: qkT[b][c][h], 512 blocks = 16 b x 32 c-slabs.
// ---------------------------------------------------------------------------
__global__ __launch_bounds__(256) void k_qk(const float* __restrict__ audio,
                                            const float* __restrict__ Wq,
                                            const float* __restrict__ Wkv,
                                            float* __restrict__ qkT) {
    const int blk = blockIdx.x;
    const int b   = blk >> 5;
    const int c0  = (blk & 31) * 8;
    const int t   = threadIdx.x;
    __shared__ float aud[DIMC];
    __shared__ float qL[DIMC];
    aud[t] = audio[b * DIMC + t];
    __syncthreads();
    {
        const float* wr = Wq + (size_t)t * DIMC;
        float acc = 0.f;
        for (int c = 0; c < DIMC; c += 4) {
            float4 w = *(const float4*)(wr + c);
            acc = fmaf(w.x, aud[c],     acc);
            acc = fmaf(w.y, aud[c + 1], acc);
            acc = fmaf(w.z, aud[c + 2], acc);
            acc = fmaf(w.w, aud[c + 3], acc);
        }
        qL[t] = acc;
    }
    __syncthreads();
    if (t < 64) {
        const int c = c0 + (t & 7);
        const int h = t >> 3;
        float acc = 0.f;
#pragma unroll
        for (int d = 0; d < 32; ++d)
            acc = fmaf(qL[h * 32 + d], Wkv[(size_t)(h * 32 + d) * DIMC + c], acc);
        qkT[((size_t)b * DIMC + c) * NH + h] = ATT_SCALE * acc;
    }
}

// ---------------------------------------------------------------------------
// K1: attn pass (R9 verbatim). 512 blocks x 256 thr, float2, unroll 8.
// ---------------------------------------------------------------------------
__global__ __launch_bounds__(256) void k_attn(const float* __restrict__ fm,
                                              const float* __restrict__ qkT,
                                              float* __restrict__ a) {
    int blk  = blockIdx.x;          // 512 = b*32 + nblk
    int b    = blk >> 5;
    int nblk = blk & 31;
    int t    = threadIdx.x;

    const int n0 = nblk * 512 + t * 2;
    const float* fmb = fm + (size_t)b * DIMC * NPIX + n0;
    const float* qb  = qkT + (size_t)b * DIMC * NH;

    float a0[NH], a1[NH];
#pragma unroll
    for (int h = 0; h < NH; ++h) { a0[h] = 0.f; a1[h] = 0.f; }

#pragma unroll 8
    for (int c = 0; c < DIMC; ++c) {
        float2 v  = *(const float2*)(fmb + (size_t)c * NPIX);
        float4 q0 = *(const float4*)(qb + c * NH);       // uniform -> s_load
        float4 q1 = *(const float4*)(qb + c * NH + 4);
        a0[0] = fmaf(v.x, q0.x, a0[0]); a1[0] = fmaf(v.y, q0.x, a1[0]);
        a0[1] = fmaf(v.x, q0.y, a0[1]); a1[1] = fmaf(v.y, q0.y, a1[1]);
        a0[2] = fmaf(v.x, q0.z, a0[2]); a1[2] = fmaf(v.y, q0.z, a1[2]);
        a0[3] = fmaf(v.x, q0.w, a0[3]); a1[3] = fmaf(v.y, q0.w, a1[3]);
        a0[4] = fmaf(v.x, q1.x, a0[4]); a1[4] = fmaf(v.y, q1.x, a1[4]);
        a0[5] = fmaf(v.x, q1.y, a0[5]); a1[5] = fmaf(v.y, q1.y, a1[5]);
        a0[6] = fmaf(v.x, q1.z, a0[6]); a1[6] = fmaf(v.y, q1.z, a1[6]);
        a0[7] = fmaf(v.x, q1.w, a0[7]); a1[7] = fmaf(v.y, q1.w, a1[7]);
    }

#pragma unroll
    for (int h = 0; h < NH; ++h) {
        float2 o;
        o.x = rintf(fminf(fmaxf(a0[h], 0.f), 4.f)) * 0.25f;
        o.y = rintf(fminf(fmaxf(a1[h], 0.f), 4.f)) * 0.25f;
        *(float2*)(a + ((size_t)b * NH + h) * NPIX + n0) = o;
    }
}

// ---------------------------------------------------------------------------
// K2: s partials, a-load amortized over 4 c per thread.
// grid = 1024 XCD-swizzled = 16 b x 16 nblk(1024 n) x 4 cq(64 c);
// 4 blk/CU = 16 waves/CU. Thread = (cg 16, nq 16): owns 4 consecutive c rows
// and one n-quad column. Per j: 8 av loads (shared across 4 c) + 4 fm loads
// -> 12 VMEM per 64 c-elements (was 36). nq-reduce via 16-lane shfl_xor,
// no LDS.
// ---------------------------------------------------------------------------
__global__ __launch_bounds__(256) void k_s(const float* __restrict__ fm,
                                           const float* __restrict__ a,
                                           float* __restrict__ s_part) {
    const int d    = blockIdx.x;
    const int blk  = (d & 7) * 128 + (d >> 3);   // bijective: 1024 = 8 x 128
    const int b    = blk >> 6;                   // 64 blocks per b
    const int nblk = (blk >> 2) & 15;            // 16 n-slabs
    const int cq   = blk & 3;                    // 4 c-quarters
    const int t    = threadIdx.x;
    const int cg   = t >> 4;                     // 0..15
    const int nq   = t & 15;
    const int c0   = cq * 64 + cg * 4;
    const int n0   = nblk * 1024;

    const float* fr = fm + ((size_t)b * DIMC + c0) * NPIX + n0 + nq * 4;
    const float* ab = a + (size_t)b * NH * NPIX + n0 + nq * 4;

    float acc[4][NH];
#pragma unroll
    for (int k = 0; k < 4; ++k)
#pragma unroll
        for (int h = 0; h < NH; ++h) acc[k][h] = 0.f;

#pragma unroll 2
    for (int j = 0; j < 16; ++j) {
        float4 av[NH];
#pragma unroll
        for (int h = 0; h < NH; ++h)
            av[h] = *(const float4*)(ab + (size_t)h * NPIX + j * 64);
#pragma unroll
        for (int k = 0; k < 4; ++k) {
            float4 v = *(const float4*)(fr + (size_t)k * NPIX + j * 64);
#pragma unroll
            for (int h = 0; h < NH; ++h)
                acc[k][h] += fmaf(v.x, av[h].x,
                             fmaf(v.y, av[h].y,
                             fmaf(v.z, av[h].z, v.w * av[h].w)));
        }
    }

    // reduce over the 16 nq lanes (contiguous within the wave)
#pragma unroll
    for (int k = 0; k < 4; ++k)
#pragma unroll
        for (int h = 0; h < NH; ++h) {
            float x = acc[k][h];
            x += __shfl_xor(x, 1);
            x += __shfl_xor(x, 2);
            x += __shfl_xor(x, 4);
            x += __shfl_xor(x, 8);
            acc[k][h] = x;
        }

    if (nq == 0) {
#pragma unroll
        for (int k = 0; k < 4; ++k)
#pragma unroll
            for (int h = 0; h < NH; ++h)
                s_part[(((size_t)b * NBLK_S + nblk) * NH + h) * DIMC + c0 + k] = acc[k][h];
    }
}

// ---------------------------------------------------------------------------
// K3: s = sum_slab s_part ; x = Wv*s ; p = Wp*x + bp ; LN ; spike -> scale
// ---------------------------------------------------------------------------
__global__ __launch_bounds__(256) void k_scale(const float* __restrict__ s_part,
                                               const float* __restrict__ Wkv,
                                               const float* __restrict__ Wp,
                                               const float* __restrict__ bp,
                                               const float* __restrict__ g,
                                               const float* __restrict__ beta,
                                               float* __restrict__ scale) {
    int b = blockIdx.x;
    int t = threadIdx.x;
    __shared__ float sL[NH][DIMC];
    __shared__ float xL[DIMC];
    __shared__ float red[8];
    __shared__ float mu_s, var_s;

    for (int h = 0; h < NH; ++h) {
        float acc = 0.f;
        for (int sl = 0; sl < NBLK_S; ++sl)
            acc += s_part[(((size_t)b * NBLK_S + sl) * NH + h) * DIMC + t];
        sL[h][t] = acc;
    }
    __syncthreads();

    {
        const float* wr = Wkv + (size_t)(DIMC + t) * DIMC;
        const float* sr = sL[t >> 5];
        float acc = 0.f;
        for (int cc = 0; cc < DIMC; cc += 4) {
            float4 w = *(const float4*)(wr + cc);
            acc = fmaf(w.x, sr[cc],     acc);
            acc = fmaf(w.y, sr[cc + 1], acc);
            acc = fmaf(w.z, sr[cc + 2], acc);
            acc = fmaf(w.w, sr[cc + 3], acc);
        }
        xL[t] = acc;
    }
    __syncthreads();

    float p;
    {
        const float* wr = Wp + (size_t)t * DIMC;
        float acc = 0.f;
        for (int i = 0; i < DIMC; i += 4) {
            float4 w = *(const float4*)(wr + i);
            acc = fmaf(w.x, xL[i],     acc);
            acc = fmaf(w.y, xL[i + 1], acc);
            acc = fmaf(w.z, xL[i + 2], acc);
            acc = fmaf(w.w, xL[i + 3], acc);
        }
        p = acc + bp[t];
    }

    int lane = t & 63, wid = t >> 6;
    float r = p;
#pragma unroll
    for (int off = 32; off > 0; off >>= 1) r += __shfl_down(r, off);
    if (lane == 0) red[wid] = r;
    __syncthreads();
    if (t == 0) mu_s = (red[0] + red[1] + red[2] + red[3]) * (1.f / 256.f);
    __syncthreads();
    float mu = mu_s;
    float dd = p - mu;
    float r2 = dd * dd;
#pragma unroll
    for (int off = 32; off > 0; off >>= 1) r2 += __shfl_down(r2, off);
    if (lane == 0) red[4 + wid] = r2;
    __syncthreads();
    if (t == 0) var_s = (red[4] + red[5] + red[6] + red[7]) * (1.f / 256.f);
    __syncthreads();

    float ln = dd * (1.0f / sqrtf(var_s + LN_EPS)) * g[t] + beta[t];
    scale[b * DIMC + t] = rintf(fminf(fmaxf(ln, 0.f), 4.f)) * 0.25f;
}

// ---------------------------------------------------------------------------
// K4: out = fm * scale[b][c], NT stores, coalesced dual-issue (R20-verified).
// ---------------------------------------------------------------------------
__global__ __launch_bounds__(256) void k_out(const float* __restrict__ fm,
                                             const float* __restrict__ scale,
                                             float* __restrict__ out) {
    const size_t total4 = (size_t)BATCH * DIMC * NPIX / 4;   // 16,777,216
    const size_t tile   = 512;                                // float4 per block-iter
    const size_t stride = (size_t)gridDim.x * tile;
    const int t = threadIdx.x;
    for (size_t base = (size_t)blockIdx.x * tile; base < total4; base += stride) {
        size_t i0 = base + t;
        size_t i1 = base + t + 256;
        vfloat4 v0 = *(const vfloat4*)(fm + i0 * 4);
        vfloat4 v1 = *(const vfloat4*)(fm + i1 * 4);
        float s0 = scale[i0 >> 12];
        float s1 = scale[i1 >> 12];
        vfloat4 o0 = v0 * s0;
        vfloat4 o1 = v1 * s1;
        __builtin_nontemporal_store(o0, (vfloat4*)(out + i0 * 4));
        __builtin_nontemporal_store(o1, (vfloat4*)(out + i1 * 4));
    }
}

// ---------------------------------------------------------------------------
extern "C" void kernel_launch(void* const* d_in, const int* in_sizes, int n_in,
                              void* d_out, int out_size, void* d_ws, size_t ws_size,
                              hipStream_t stream) {
    (void)in_sizes; (void)n_in; (void)out_size; (void)ws_size;
    const float* fm    = (const float*)d_in[0];
    const float* audio = (const float*)d_in[1];
    const float* Wq    = (const float*)d_in[2];
    const float* Wkv   = (const float*)d_in[3];
    const float* Wp    = (const float*)d_in[4];
    const float* bp    = (const float*)d_in[5];
    const float* g     = (const float*)d_in[6];
    const float* beta  = (const float*)d_in[7];
    float* out = (float*)d_out;

    char* ws = (char*)d_ws;
    float* qkT    = (float*)(ws);                                   // 128 KB
    float* a      = (float*)(ws + (size_t)131072);                  // 8 MB
    float* s_part = (float*)(ws + (size_t)131072 + 8388608);        // 2 MB
    float* scale  = (float*)(ws + (size_t)131072 + 8388608 + 2097152); // 16 KB

    hipLaunchKernelGGL(k_qk,    dim3(512),        dim3(256), 0, stream, audio, Wq, Wkv, qkT);
    hipLaunchKernelGGL(k_attn,  dim3(512),        dim3(256), 0, stream, fm, qkT, a);
    hipLaunchKernelGGL(k_s,     dim3(1024),       dim3(256), 0, stream, fm, a, s_part);
    hipLaunchKernelGGL(k_scale, dim3(BATCH),      dim3(256), 0, stream, s_part, Wkv, Wp, bp, g, beta, scale);
    hipLaunchKernelGGL(k_out,   dim3(2048),       dim3(256), 0, stream, fm, scale, out);
}

// Round 23
// 211.252 us; speedup vs baseline: 1.1496x; 1.0111x over previous
//
#include <hip/hip_runtime.h>
#include <math.h>

#define DIMC 256
#define NH 8
#define NPIX 16384          // 128*128
#define BATCH 16
#define ATT_SCALE 0.17677669529663687f   // 1/sqrt(32)
#define LN_EPS 1e-5f
#define NBLK_S 16           // n-slabs in k_s (1024 n each)

typedef float vfloat4 __attribute__((ext_vector_type(4)));   // native vector for nt store

// ---------------------------------------------------------------------------
// K0: qkT[b][c][h], 512 blocks = 16 b x 32 c-slabs.
// ---------------------------------------------------------------------------
__global__ __launch_bounds__(256) void k_qk(const float* __restrict__ audio,
                                            const float* __restrict__ Wq,
                                            const float* __restrict__ Wkv,
                                            float* __restrict__ qkT) {
    const int blk = blockIdx.x;
    const int b   = blk >> 5;
    const int c0  = (blk & 31) * 8;
    const int t   = threadIdx.x;
    __shared__ float aud[DIMC];
    __shared__ float qL[DIMC];
    aud[t] = audio[b * DIMC + t];
    __syncthreads();
    {
        const float* wr = Wq + (size_t)t * DIMC;
        float acc = 0.f;
        for (int c = 0; c < DIMC; c += 4) {
            float4 w = *(const float4*)(wr + c);
            acc = fmaf(w.x, aud[c],     acc);
            acc = fmaf(w.y, aud[c + 1], acc);
            acc = fmaf(w.z, aud[c + 2], acc);
            acc = fmaf(w.w, aud[c + 3], acc);
        }
        qL[t] = acc;
    }
    __syncthreads();
    if (t < 64) {
        const int c = c0 + (t & 7);
        const int h = t >> 3;
        float acc = 0.f;
#pragma unroll
        for (int d = 0; d < 32; ++d)
            acc = fmaf(qL[h * 32 + d], Wkv[(size_t)(h * 32 + d) * DIMC + c], acc);
        qkT[((size_t)b * DIMC + c) * NH + h] = ATT_SCALE * acc;
    }
}

// ---------------------------------------------------------------------------
// K1: attn pass (R9 verbatim). 512 blocks x 256 thr, float2, unroll 8.
// ---------------------------------------------------------------------------
__global__ __launch_bounds__(256) void k_attn(const float* __restrict__ fm,
                                              const float* __restrict__ qkT,
                                              float* __restrict__ a) {
    int blk  = blockIdx.x;          // 512 = b*32 + nblk
    int b    = blk >> 5;
    int nblk = blk & 31;
    int t    = threadIdx.x;

    const int n0 = nblk * 512 + t * 2;
    const float* fmb = fm + (size_t)b * DIMC * NPIX + n0;
    const float* qb  = qkT + (size_t)b * DIMC * NH;

    float a0[NH], a1[NH];
#pragma unroll
    for (int h = 0; h < NH; ++h) { a0[h] = 0.f; a1[h] = 0.f; }

#pragma unroll 8
    for (int c = 0; c < DIMC; ++c) {
        float2 v  = *(const float2*)(fmb + (size_t)c * NPIX);
        float4 q0 = *(const float4*)(qb + c * NH);       // uniform -> s_load
        float4 q1 = *(const float4*)(qb + c * NH + 4);
        a0[0] = fmaf(v.x, q0.x, a0[0]); a1[0] = fmaf(v.y, q0.x, a1[0]);
        a0[1] = fmaf(v.x, q0.y, a0[1]); a1[1] = fmaf(v.y, q0.y, a1[1]);
        a0[2] = fmaf(v.x, q0.z, a0[2]); a1[2] = fmaf(v.y, q0.z, a1[2]);
        a0[3] = fmaf(v.x, q0.w, a0[3]); a1[3] = fmaf(v.y, q0.w, a1[3]);
        a0[4] = fmaf(v.x, q1.x, a0[4]); a1[4] = fmaf(v.y, q1.x, a1[4]);
        a0[5] = fmaf(v.x, q1.y, a0[5]); a1[5] = fmaf(v.y, q1.y, a1[5]);
        a0[6] = fmaf(v.x, q1.z, a0[6]); a1[6] = fmaf(v.y, q1.z, a1[6]);
        a0[7] = fmaf(v.x, q1.w, a0[7]); a1[7] = fmaf(v.y, q1.w, a1[7]);
    }

#pragma unroll
    for (int h = 0; h < NH; ++h) {
        float2 o;
        o.x = rintf(fminf(fmaxf(a0[h], 0.f), 4.f)) * 0.25f;
        o.y = rintf(fminf(fmaxf(a1[h], 0.f), 4.f)) * 0.25f;
        *(float2*)(a + ((size_t)b * NH + h) * NPIX + n0) = o;
    }
}

// ---------------------------------------------------------------------------
// K2: s partials, a-load amortized over 4 c per thread (R22-verified).
// grid = 1024 XCD-swizzled = 16 b x 16 nblk(1024 n) x 4 cq(64 c).
// ---------------------------------------------------------------------------
__global__ __launch_bounds__(256) void k_s(const float* __restrict__ fm,
                                           const float* __restrict__ a,
                                           float* __restrict__ s_part) {
    const int d    = blockIdx.x;
    const int blk  = (d & 7) * 128 + (d >> 3);   // bijective: 1024 = 8 x 128
    const int b    = blk >> 6;                   // 64 blocks per b
    const int nblk = (blk >> 2) & 15;            // 16 n-slabs
    const int cq   = blk & 3;                    // 4 c-quarters
    const int t    = threadIdx.x;
    const int cg   = t >> 4;                     // 0..15
    const int nq   = t & 15;
    const int c0   = cq * 64 + cg * 4;
    const int n0   = nblk * 1024;

    const float* fr = fm + ((size_t)b * DIMC + c0) * NPIX + n0 + nq * 4;
    const float* ab = a + (size_t)b * NH * NPIX + n0 + nq * 4;

    float acc[4][NH];
#pragma unroll
    for (int k = 0; k < 4; ++k)
#pragma unroll
        for (int h = 0; h < NH; ++h) acc[k][h] = 0.f;

#pragma unroll 2
    for (int j = 0; j < 16; ++j) {
        float4 av[NH];
#pragma unroll
        for (int h = 0; h < NH; ++h)
            av[h] = *(const float4*)(ab + (size_t)h * NPIX + j * 64);
#pragma unroll
        for (int k = 0; k < 4; ++k) {
            float4 v = *(const float4*)(fr + (size_t)k * NPIX + j * 64);
#pragma unroll
            for (int h = 0; h < NH; ++h)
                acc[k][h] += fmaf(v.x, av[h].x,
                             fmaf(v.y, av[h].y,
                             fmaf(v.z, av[h].z, v.w * av[h].w)));
        }
    }

    // reduce over the 16 nq lanes (contiguous within the wave)
#pragma unroll
    for (int k = 0; k < 4; ++k)
#pragma unroll
        for (int h = 0; h < NH; ++h) {
            float x = acc[k][h];
            x += __shfl_xor(x, 1);
            x += __shfl_xor(x, 2);
            x += __shfl_xor(x, 4);
            x += __shfl_xor(x, 8);
            acc[k][h] = x;
        }

    if (nq == 0) {
#pragma unroll
        for (int k = 0; k < 4; ++k)
#pragma unroll
            for (int h = 0; h < NH; ++h)
                s_part[(((size_t)b * NBLK_S + nblk) * NH + h) * DIMC + c0 + k] = acc[k][h];
    }
}

// ---------------------------------------------------------------------------
// K3: s = sum_slab s_part ; x = Wv*s ; p = Wp*x + bp ; LN ; spike -> scale
// ---------------------------------------------------------------------------
__global__ __launch_bounds__(256) void k_scale(const float* __restrict__ s_part,
                                               const float* __restrict__ Wkv,
                                               const float* __restrict__ Wp,
                                               const float* __restrict__ bp,
                                               const float* __restrict__ g,
                                               const float* __restrict__ beta,
                                               float* __restrict__ scale) {
    int b = blockIdx.x;
    int t = threadIdx.x;
    __shared__ float sL[NH][DIMC];
    __shared__ float xL[DIMC];
    __shared__ float red[8];
    __shared__ float mu_s, var_s;

    for (int h = 0; h < NH; ++h) {
        float acc = 0.f;
        for (int sl = 0; sl < NBLK_S; ++sl)
            acc += s_part[(((size_t)b * NBLK_S + sl) * NH + h) * DIMC + t];
        sL[h][t] = acc;
    }
    __syncthreads();

    {
        const float* wr = Wkv + (size_t)(DIMC + t) * DIMC;
        const float* sr = sL[t >> 5];
        float acc = 0.f;
        for (int cc = 0; cc < DIMC; cc += 4) {
            float4 w = *(const float4*)(wr + cc);
            acc = fmaf(w.x, sr[cc],     acc);
            acc = fmaf(w.y, sr[cc + 1], acc);
            acc = fmaf(w.z, sr[cc + 2], acc);
            acc = fmaf(w.w, sr[cc + 3], acc);
        }
        xL[t] = acc;
    }
    __syncthreads();

    float p;
    {
        const float* wr = Wp + (size_t)t * DIMC;
        float acc = 0.f;
        for (int i = 0; i < DIMC; i += 4) {
            float4 w = *(const float4*)(wr + i);
            acc = fmaf(w.x, xL[i],     acc);
            acc = fmaf(w.y, xL[i + 1], acc);
            acc = fmaf(w.z, xL[i + 2], acc);
            acc = fmaf(w.w, xL[i + 3], acc);
        }
        p = acc + bp[t];
    }

    int lane = t & 63, wid = t >> 6;
    float r = p;
#pragma unroll
    for (int off = 32; off > 0; off >>= 1) r += __shfl_down(r, off);
    if (lane == 0) red[wid] = r;
    __syncthreads();
    if (t == 0) mu_s = (red[0] + red[1] + red[2] + red[3]) * (1.f / 256.f);
    __syncthreads();
    float mu = mu_s;
    float dd = p - mu;
    float r2 = dd * dd;
#pragma unroll
    for (int off = 32; off > 0; off >>= 1) r2 += __shfl_down(r2, off);
    if (lane == 0) red[4 + wid] = r2;
    __syncthreads();
    if (t == 0) var_s = (red[4] + red[5] + red[6] + red[7]) * (1.f / 256.f);
    __syncthreads();

    float ln = dd * (1.0f / sqrtf(var_s + LN_EPS)) * g[t] + beta[t];
    scale[b * DIMC + t] = rintf(fminf(fmaxf(ln, 0.f), 4.f)) * 0.25f;
}

// ---------------------------------------------------------------------------
// K4: out = fm * scale[b][c], NT stores, ILP x4 (tile 1024 float4) and
// 4096 blocks (16 blk/CU): doubles both per-thread write depth and the
// number of waves issuing NT stores concurrently. Each of the 4 store
// instructions is a dense 16B/lane burst (coalescing preserved).
// ---------------------------------------------------------------------------
__global__ __launch_bounds__(256) void k_out(const float* __restrict__ fm,
                                             const float* __restrict__ scale,
                                             float* __restrict__ out) {
    const size_t total4 = (size_t)BATCH * DIMC * NPIX / 4;   // 16,777,216
    const size_t tile   = 1024;                               // float4 per block-iter
    const size_t stride = (size_t)gridDim.x * tile;
    const int t = threadIdx.x;
    for (size_t base = (size_t)blockIdx.x * tile; base < total4; base += stride) {
        size_t i0 = base + t;
        size_t i1 = base + t + 256;
        size_t i2 = base + t + 512;
        size_t i3 = base + t + 768;
        vfloat4 v0 = *(const vfloat4*)(fm + i0 * 4);
        vfloat4 v1 = *(const vfloat4*)(fm + i1 * 4);
        vfloat4 v2 = *(const vfloat4*)(fm + i2 * 4);
        vfloat4 v3 = *(const vfloat4*)(fm + i3 * 4);
        float s0 = scale[i0 >> 12];
        float s1 = scale[i1 >> 12];
        float s2 = scale[i2 >> 12];
        float s3 = scale[i3 >> 12];
        vfloat4 o0 = v0 * s0;
        vfloat4 o1 = v1 * s1;
        vfloat4 o2 = v2 * s2;
        vfloat4 o3 = v3 * s3;
        __builtin_nontemporal_store(o0, (vfloat4*)(out + i0 * 4));
        __builtin_nontemporal_store(o1, (vfloat4*)(out + i1 * 4));
        __builtin_nontemporal_store(o2, (vfloat4*)(out + i2 * 4));
        __builtin_nontemporal_store(o3, (vfloat4*)(out + i3 * 4));
    }
}

// ---------------------------------------------------------------------------
extern "C" void kernel_launch(void* const* d_in, const int* in_sizes, int n_in,
                              void* d_out, int out_size, void* d_ws, size_t ws_size,
                              hipStream_t stream) {
    (void)in_sizes; (void)n_in; (void)out_size; (void)ws_size;
    const float* fm    = (const float*)d_in[0];
    const float* audio = (const float*)d_in[1];
    const float* Wq    = (const float*)d_in[2];
    const float* Wkv   = (const float*)d_in[3];
    const float* Wp    = (const float*)d_in[4];
    const float* bp    = (const float*)d_in[5];
    const float* g     = (const float*)d_in[6];
    const float* beta  = (const float*)d_in[7];
    float* out = (float*)d_out;

    char* ws = (char*)d_ws;
    float* qkT    = (float*)(ws);                                   // 128 KB
    float* a      = (float*)(ws + (size_t)131072);                  // 8 MB
    float* s_part = (float*)(ws + (size_t)131072 + 8388608);        // 2 MB
    float* scale  = (float*)(ws + (size_t)131072 + 8388608 + 2097152); // 16 KB

    hipLaunchKernelGGL(k_qk,    dim3(512),        dim3(256), 0, stream, audio, Wq, Wkv, qkT);
    hipLaunchKernelGGL(k_attn,  dim3(512),        dim3(256), 0, stream, fm, qkT, a);
    hipLaunchKernelGGL(k_s,     dim3(1024),       dim3(256), 0, stream, fm, a, s_part);
    hipLaunchKernelGGL(k_scale, dim3(BATCH),      dim3(256), 0, stream, s_part, Wkv, Wp, bp, g, beta, scale);
    hipLaunchKernelGGL(k_out,   dim3(4096),       dim3(256), 0, stream, fm, scale, out);
}